// Round 2
// baseline (1720.711 us; speedup 1.0000x reference)
//
#include <hip/hip_runtime.h>
#include <math.h>

typedef _Float16 h16;
typedef __attribute__((ext_vector_type(8))) _Float16 half8;  // 8 fp16 = 4 VGPRs (MFMA A/B frag)
typedef __attribute__((ext_vector_type(4))) float float4v;   // MFMA C/D frag

// Problem constants
#define BB 16
#define NN 4096
#define KK 64
#define DD 1024
#define HH 8

// ---------------------------------------------------------------------------
// Generic NT GEMM:  C[M,N] = scale * (A[M,Kd] · B[N,Kd]^T) + bias[n] + resid
// A, B fp16 row-major (contraction along contiguous inner dim for BOTH).
// Output to Cf (fp32) or Ch (fp16). Optional batch via blockIdx.z strides.
// m93/m97 structure — BK=32, global_load_lds width 16, 16x16x32 f16 MFMA.
// ---------------------------------------------------------------------------
template<int BM, int BN, int WM, int WN>
__global__ __launch_bounds__(256)
void gemm_nt(const h16* __restrict__ A, const h16* __restrict__ B,
             float* Cf, h16* Ch,
             const float* __restrict__ bias, const float* resid,
             float scale, int Kd, int lda, int ldb, int ldc,
             long sA, long sB, long sC)
{
  constexpr int BK = 32;
  constexpr int WAVES_N = BN / WN;
  constexpr int TM = WM / 16, TN = WN / 16;
  __shared__ alignas(16) h16 Ast[BM * BK];
  __shared__ alignas(16) h16 Bst[BN * BK];
  const int tid  = threadIdx.x;
  const int lane = tid & 63, wave = tid >> 6;
  const int wm = wave / WAVES_N, wn = wave % WAVES_N;
  const int bn = blockIdx.x, bm = blockIdx.y, bz = blockIdx.z;
  const h16* Ab = A + (long)bz * sA;
  const h16* Bb = B + (long)bz * sB;
  const int rowA0 = bm * BM, rowB0 = bn * BN;
  // staging: chunk = 1024 LDS bytes = 512 fp16 = 16 tile rows; lane writes 16B
  const int lrow = lane >> 2;        // row within chunk
  const int lcol = (lane & 3) * 8;   // col (k) within row

  float4v acc[TM][TN];
  const float4v fzero = {0.f, 0.f, 0.f, 0.f};
  for (int i = 0; i < TM; i++)
    for (int j = 0; j < TN; j++) acc[i][j] = fzero;

  for (int k0 = 0; k0 < Kd; k0 += BK) {
    __syncthreads();   // previous iter's LDS reads done before overwrite
    for (int c = wave; c < BM/16; c += 4) {
      const h16* g = Ab + (long)(rowA0 + c*16 + lrow) * lda + (k0 + lcol);
      __builtin_amdgcn_global_load_lds((__attribute__((address_space(1))) const void*)g,
          (__attribute__((address_space(3))) void*)(Ast + c*512), 16, 0, 0);
    }
    for (int c = wave; c < BN/16; c += 4) {
      const h16* g = Bb + (long)(rowB0 + c*16 + lrow) * ldb + (k0 + lcol);
      __builtin_amdgcn_global_load_lds((__attribute__((address_space(1))) const void*)g,
          (__attribute__((address_space(3))) void*)(Bst + c*512), 16, 0, 0);
    }
    __syncthreads();   // s_waitcnt vmcnt(0) before s_barrier → staging visible

    // A-operand frag: A[m = lane&15][k = (lane>>4)*8 + j]
    const int fr = lane & 15, kq = (lane >> 4) * 8;
    half8 af[TM], bfr[TN];
    #pragma unroll
    for (int t = 0; t < TM; t++)
      af[t] = *(const half8*)(Ast + (wm*WM + t*16 + fr)*BK + kq);
    #pragma unroll
    for (int u = 0; u < TN; u++)
      bfr[u] = *(const half8*)(Bst + (wn*WN + u*16 + fr)*BK + kq);
    #pragma unroll
    for (int t = 0; t < TM; t++)
      #pragma unroll
      for (int u = 0; u < TN; u++)
        acc[t][u] = __builtin_amdgcn_mfma_f32_16x16x32_f16(af[t], bfr[u], acc[t][u], 0, 0, 0);
  }

  // C/D layout (m89-verified, dtype-independent): col = lane&15, row = (lane>>4)*4 + reg
  const int r0 = rowA0 + wm*WM + (lane >> 4) * 4;
  const int c0 = rowB0 + wn*WN + (lane & 15);
  float* Cfb = Cf ? Cf + (long)bz * sC : (float*)0;
  h16*   Chb = Ch ? Ch + (long)bz * sC : (h16*)0;
  const float* rb = resid ? resid + (long)bz * sC : (const float*)0;
  #pragma unroll
  for (int t = 0; t < TM; t++) {
    #pragma unroll
    for (int u = 0; u < TN; u++) {
      const int col = c0 + u*16;
      const float bv = bias ? bias[col] : 0.f;
      #pragma unroll
      for (int r = 0; r < 4; r++) {
        const long idx = (long)(r0 + t*16 + r) * ldc + col;
        float vv = acc[t][u][r] * scale + bv;
        if (rb) vv += rb[idx];
        if (Cfb) Cfb[idx] = vv; else Chb[idx] = (h16)vv;
      }
    }
  }
}

// ---------------------------------------------------------------------------
// LayerNorm over D=1024 (one block per row). Optional fused add (x + add).
// Writes fp32 and/or fp16. fp32 math throughout.
// ---------------------------------------------------------------------------
__global__ __launch_bounds__(256)
void ln_kernel(const float* x, const float* add,
               const float* __restrict__ g, const float* __restrict__ b,
               float* outf, h16* outh)
{
  const int row = blockIdx.x, t = threadIdx.x;
  const long rb_ = (long)row * DD;
  float v[4]; float s = 0.f, s2 = 0.f;
  #pragma unroll
  for (int i = 0; i < 4; i++) {
    const int c = t + i*256;
    float xv = x[rb_ + c];
    if (add) xv += add[rb_ + c];
    v[i] = xv; s += xv; s2 += xv*xv;
  }
  #pragma unroll
  for (int off = 32; off > 0; off >>= 1) {
    s  += __shfl_down(s,  off, 64);
    s2 += __shfl_down(s2, off, 64);
  }
  __shared__ float red[8];
  const int lane = t & 63, w = t >> 6;
  if (lane == 0) { red[w] = s; red[4+w] = s2; }
  __syncthreads();
  const float S  = red[0]+red[1]+red[2]+red[3];
  const float S2 = red[4]+red[5]+red[6]+red[7];
  const float mean = S * (1.f/DD);
  const float var  = S2 * (1.f/DD) - mean*mean;
  const float rinv = rsqrtf(var + 1e-5f);
  #pragma unroll
  for (int i = 0; i < 4; i++) {
    const int c = t + i*256;
    const float y = (v[i] - mean) * rinv * g[c] + b[c];
    if (outf) outf[rb_ + c] = y;
    if (outh) outh[rb_ + c] = (h16)y;
  }
}

// Softmax over the SLOT axis (axis=1 of [B,K=64,N]): one thread per (b,n).
__global__ __launch_bounds__(256)
void softmax_slots(const float* __restrict__ attn, h16* __restrict__ aw)
{
  const long idx = (long)blockIdx.x * 256 + threadIdx.x;  // b*N + n
  const int b = (int)(idx >> 12), n = (int)(idx & 4095);
  const float* p = attn + ((long)b << 18) + n;            // b*64*4096
  float vals[64]; float mx = -1e30f;
  #pragma unroll
  for (int k = 0; k < 64; k++) { vals[k] = p[(long)k << 12]; mx = fmaxf(mx, vals[k]); }
  float sum = 0.f;
  #pragma unroll
  for (int k = 0; k < 64; k++) { const float e = __expf(vals[k] - mx); vals[k] = e; sum += e; }
  const float r = 1.f / sum;
  h16* q = aw + ((long)b << 18) + n;
  #pragma unroll
  for (int k = 0; k < 64; k++) q[(long)k << 12] = (h16)(vals[k] * r);
}

// Slot self-attention MHA: one block per (b,h). seq=64, dh=128. LDS-resident.
__global__ __launch_bounds__(256)
void mha_kernel(const float* __restrict__ qkv, float* __restrict__ sa)
{
  const int b = blockIdx.x >> 3, h = blockIdx.x & 7;
  __shared__ h16   mk[64][128];
  __shared__ h16   mv[64][128];
  __shared__ float sc[64][64];
  const int t = threadIdx.x;
  const long base = ((long)b * 64) * (3*DD) + h * 128;
  for (int i = t; i < 64*128; i += 256) {
    const int r = i >> 7, d = i & 127;
    mk[r][d] = (h16)qkv[base + (long)r*(3*DD) + DD   + d];
    mv[r][d] = (h16)qkv[base + (long)r*(3*DD) + 2*DD + d];
  }
  __syncthreads();
  {  // scores: thread t -> q = t>>2, k2 range (t&3)*16..+16
    const int q = t >> 2, kb2 = (t & 3) * 16;
    float accv[16];
    #pragma unroll
    for (int i = 0; i < 16; i++) accv[i] = 0.f;
    const float* mq = qkv + base + (long)q * (3*DD);
    for (int d0 = 0; d0 < 128; d0 += 8) {
      float qr[8];
      #pragma unroll
      for (int j = 0; j < 8; j++) qr[j] = mq[d0 + j];
      #pragma unroll
      for (int i = 0; i < 16; i++) {
        float sacc = 0.f;
        #pragma unroll
        for (int j = 0; j < 8; j++) sacc += qr[j] * (float)(mk[kb2+i][d0+j]);
        accv[i] += sacc;
      }
    }
    #pragma unroll
    for (int i = 0; i < 16; i++) sc[q][kb2+i] = accv[i] * 0.088388347648318447f; // 1/sqrt(128)
  }
  __syncthreads();
  if (t < 64) {  // softmax over keys (axis=-1), row t
    float mx = -1e30f;
    for (int i = 0; i < 64; i++) mx = fmaxf(mx, sc[t][i]);
    float sum = 0.f;
    for (int i = 0; i < 64; i++) { const float e = __expf(sc[t][i] - mx); sc[t][i] = e; sum += e; }
    const float r = 1.f / sum;
    for (int i = 0; i < 64; i++) sc[t][i] *= r;
  }
  __syncthreads();
  {  // out: thread t -> q = t>>2, d range (t&3)*32..+32
    const int q = t >> 2, d0 = (t & 3) * 32;
    float o[32];
    #pragma unroll
    for (int i = 0; i < 32; i++) o[i] = 0.f;
    for (int k2 = 0; k2 < 64; k2++) {
      const float p = sc[q][k2];
      #pragma unroll
      for (int i = 0; i < 32; i++) o[i] += p * (float)(mv[k2][d0+i]);
    }
    float* op = sa + ((long)(b*64 + q)) * DD + h*128 + d0;
    #pragma unroll
    for (int i = 0; i < 32; i++) op[i] = o[i];
  }
}

// fp32 [R,C] -> fp16 [C,R] (weight transpose+cast)
__global__ void transpose_cast(const float* __restrict__ src, h16* __restrict__ dst,
                               int R, int C)
{
  __shared__ float tile[32][33];
  const int c0 = blockIdx.x * 32, r0 = blockIdx.y * 32;
  const int tx = threadIdx.x & 31, ty = threadIdx.x >> 5;
  for (int i = ty; i < 32; i += 8) tile[i][tx] = src[(long)(r0+i)*C + c0 + tx];
  __syncthreads();
  for (int i = ty; i < 32; i += 8) dst[(long)(c0+i)*R + r0 + tx] = (h16)tile[tx][i];
}

// fp16 [z][R,C] -> fp16 [z][C,R]
__global__ void transpose_h16(const h16* __restrict__ src, h16* __restrict__ dst,
                              int R, int C)
{
  __shared__ h16 tile[32][33];
  const long zoff = (long)blockIdx.z * R * C;
  const int c0 = blockIdx.x * 32, r0 = blockIdx.y * 32;
  const int tx = threadIdx.x & 31, ty = threadIdx.x >> 5;
  for (int i = ty; i < 32; i += 8) tile[i][tx] = src[zoff + (long)(r0+i)*C + c0 + tx];
  __syncthreads();
  for (int i = ty; i < 32; i += 8) dst[zoff + (long)(c0+i)*R + r0 + tx] = tile[tx][i];
}

__global__ void cast_f32_h16(const float* __restrict__ x, h16* __restrict__ y, long n)
{
  const long i = (long)blockIdx.x * 256 + threadIdx.x;
  if (i < n) y[i] = (h16)x[i];
}

__global__ void gelu_cast(const float* __restrict__ x, h16* __restrict__ y, long n)
{
  const long i = (long)blockIdx.x * 256 + threadIdx.x;
  if (i < n) {
    const float v = x[i];
    y[i] = (h16)(0.5f * v * (1.f + erff(v * 0.70710678118654752f)));
  }
}

// slots[b*64+k][d] = slot_init[k][d]
__global__ void init_slots(const float* __restrict__ si, float* __restrict__ S)
{
  const long i = (long)blockIdx.x * 256 + threadIdx.x;   // over 1024*1024
  const int row = (int)(i >> 10), d = (int)(i & 1023);
  S[i] = si[((row & 63) << 10) + d];
}

// ---------------------------------------------------------------------------
extern "C" void kernel_launch(void* const* d_in, const int* in_sizes, int n_in,
                              void* d_out, int out_size, void* d_ws, size_t ws_size,
                              hipStream_t stream)
{
  const float* vt        = (const float*)d_in[0];
  const float* slot_init = (const float*)d_in[1];
  const float* ln_vis_g  = (const float*)d_in[2];
  const float* ln_vis_b  = (const float*)d_in[3];
  const float* ln_sl_g   = (const float*)d_in[4];
  const float* ln_sl_b   = (const float*)d_in[5];
  const float* Wq        = (const float*)d_in[6];
  const float* Wk        = (const float*)d_in[7];
  const float* Wv        = (const float*)d_in[8];
  const float* Wo        = (const float*)d_in[9];
  const float* mha_in_w  = (const float*)d_in[10];
  const float* mha_in_b  = (const float*)d_in[11];
  const float* mha_out_w = (const float*)d_in[12];
  const float* mha_out_b = (const float*)d_in[13];
  const float* ln_sa_g   = (const float*)d_in[14];
  const float* ln_sa_b   = (const float*)d_in[15];
  const float* ln_ffn_g  = (const float*)d_in[16];
  const float* ln_ffn_b  = (const float*)d_in[17];
  const float* W1        = (const float*)d_in[18];
  const float* b1        = (const float*)d_in[19];
  const float* W2        = (const float*)d_in[20];
  const float* b2        = (const float*)d_in[21];
  float* out = (float*)d_out;

  // ---- workspace layout (bump allocator, 256B aligned; total ≈ 478 MB) ----
  char* ws = (char*)d_ws;
  size_t off = 0;
  auto alloc = [&](size_t bytes) -> char* {
    char* p = ws + off; off += (bytes + 255) & ~(size_t)255; return p;
  };
  h16* wqT  = (h16*)alloc((size_t)DD*DD*2);        // [out,in]
  h16* wkT  = (h16*)alloc((size_t)DD*DD*2);
  h16* wvT  = (h16*)alloc((size_t)DD*DD*2);
  h16* woT  = (h16*)alloc((size_t)DD*DD*2);
  h16* w_in = (h16*)alloc((size_t)3*DD*DD*2);      // already [out,in]
  h16* w_ou = (h16*)alloc((size_t)DD*DD*2);
  h16* w1T  = (h16*)alloc((size_t)2*DD*DD*2);      // [2D, D]
  h16* w2T  = (h16*)alloc((size_t)2*DD*DD*2);      // [D, 2D]
  float* S       = (float*)alloc((size_t)BB*KK*DD*4);
  h16*   snb     = (h16*)alloc((size_t)BB*KK*DD*2);
  h16*   qb      = (h16*)alloc((size_t)BB*KK*DD*2);
  h16*   updb    = (h16*)alloc((size_t)BB*KK*DD*2);
  h16*   slotsb  = (h16*)alloc((size_t)BB*KK*DD*2);
  h16*   sab     = (h16*)alloc((size_t)BB*KK*DD*2);
  h16*   hb      = (h16*)alloc((size_t)BB*KK*DD*2);
  h16*   g1b     = (h16*)alloc((size_t)BB*KK*2*DD*2);
  float* qkv     = (float*)alloc((size_t)BB*KK*3*DD*4);
  float* sa      = (float*)alloc((size_t)BB*KK*DD*4);
  float* sa2     = (float*)alloc((size_t)BB*KK*DD*4);
  float* G       = (float*)alloc((size_t)BB*KK*2*DD*4);
  h16*   vnb     = (h16*)alloc((size_t)BB*NN*DD*2); // 134 MB
  h16*   kbuf    = (h16*)alloc((size_t)BB*NN*DD*2); // 134 MB
  h16*   vbuf    = (h16*)alloc((size_t)BB*NN*DD*2); // 134 MB
  h16*   vT   = vnb;                   // alias: vn dead after k/v GEMMs
  float* attn = (float*)vbuf;          // alias: v dead after transpose
  h16*   awb  = (h16*)((char*)vbuf + (size_t)BB*KK*NN*4);
  (void)in_sizes; (void)n_in; (void)out_size; (void)ws_size;

  const dim3 blk(256);

  // ---- weight prep (fp16, [out,in] layout so every GEMM is NT) ----
  transpose_cast<<<dim3(32,32,1), blk, 0, stream>>>(Wq, wqT, DD, DD);
  transpose_cast<<<dim3(32,32,1), blk, 0, stream>>>(Wk, wkT, DD, DD);
  transpose_cast<<<dim3(32,32,1), blk, 0, stream>>>(Wv, wvT, DD, DD);
  transpose_cast<<<dim3(32,32,1), blk, 0, stream>>>(Wo, woT, DD, DD);
  transpose_cast<<<dim3(64,32,1), blk, 0, stream>>>(W1, w1T, DD, 2*DD);
  transpose_cast<<<dim3(32,64,1), blk, 0, stream>>>(W2, w2T, 2*DD, DD);
  cast_f32_h16<<<dim3(12288), blk, 0, stream>>>(mha_in_w, w_in, (long)3*DD*DD);
  cast_f32_h16<<<dim3(4096),  blk, 0, stream>>>(mha_out_w, w_ou, (long)DD*DD);
  init_slots<<<dim3(4096), blk, 0, stream>>>(slot_init, S);

  // ---- phase A: vn = LN(vt); k = vn@Wk; v = vn@Wv; vT = v^T ----
  ln_kernel<<<dim3(BB*NN), blk, 0, stream>>>(vt, nullptr, ln_vis_g, ln_vis_b, nullptr, vnb);
  gemm_nt<128,128,64,64><<<dim3(8,512,1), blk, 0, stream>>>(
      vnb, wkT, nullptr, kbuf, nullptr, nullptr, 1.f, DD, DD, DD, DD, 0, 0, 0);
  gemm_nt<128,128,64,64><<<dim3(8,512,1), blk, 0, stream>>>(
      vnb, wvT, nullptr, vbuf, nullptr, nullptr, 1.f, DD, DD, DD, DD, 0, 0, 0);
  transpose_h16<<<dim3(32,128,BB), blk, 0, stream>>>(vbuf, vT, NN, DD);

  // ---- 2 slot-attention iterations ----
  for (int it = 0; it < 2; ++it) {
    ln_kernel<<<dim3(BB*KK), blk, 0, stream>>>(S, nullptr, ln_sl_g, ln_sl_b, nullptr, snb);
    gemm_nt<128,128,64,64><<<dim3(8,8,1), blk, 0, stream>>>(          // q = sn @ Wq
        snb, wqT, nullptr, qb, nullptr, nullptr, 1.f, DD, DD, DD, DD, 0, 0, 0);
    gemm_nt<64,128,64,32><<<dim3(32,1,BB), blk, 0, stream>>>(         // attn = q·k^T * D^-0.5
        qb, kbuf, attn, nullptr, nullptr, nullptr, 0.03125f, DD, DD, DD, NN,
        (long)KK*DD, (long)NN*DD, (long)KK*NN);
    softmax_slots<<<dim3(256), blk, 0, stream>>>(attn, awb);          // softmax over SLOTS
    gemm_nt<64,128,64,32><<<dim3(8,1,BB), blk, 0, stream>>>(          // upd = aw · v
        awb, vT, nullptr, updb, nullptr, nullptr, 1.f, NN, NN, NN, DD,
        (long)KK*NN, (long)DD*NN, (long)KK*DD);
    gemm_nt<128,128,64,64><<<dim3(8,8,1), blk, 0, stream>>>(          // S += upd @ Wo
        updb, woT, S, nullptr, nullptr, S, 1.f, DD, DD, DD, DD, 0, 0, 0);
    cast_f32_h16<<<dim3(4096), blk, 0, stream>>>(S, slotsb, (long)BB*KK*DD);
    gemm_nt<128,128,64,64><<<dim3(24,8,1), blk, 0, stream>>>(         // qkv = slots @ Win^T + b
        slotsb, w_in, qkv, nullptr, mha_in_b, nullptr, 1.f, DD, DD, DD, 3*DD, 0, 0, 0);
    mha_kernel<<<dim3(BB*HH), blk, 0, stream>>>(qkv, sa);
    cast_f32_h16<<<dim3(4096), blk, 0, stream>>>(sa, sab, (long)BB*KK*DD);
    gemm_nt<128,128,64,64><<<dim3(8,8,1), blk, 0, stream>>>(          // sa2 = sa @ Wout^T + b
        sab, w_ou, sa2, nullptr, mha_out_b, nullptr, 1.f, DD, DD, DD, DD, 0, 0, 0);
    ln_kernel<<<dim3(BB*KK), blk, 0, stream>>>(S, sa2, ln_sa_g, ln_sa_b, S, nullptr); // S = LN(S+sa2)
  }

  // ---- FFN tail: out = S + gelu(LN(S)@W1 + b1)@W2 + b2 ----
  ln_kernel<<<dim3(BB*KK), blk, 0, stream>>>(S, nullptr, ln_ffn_g, ln_ffn_b, nullptr, hb);
  gemm_nt<128,128,64,64><<<dim3(16,8,1), blk, 0, stream>>>(
      hb, w1T, G, nullptr, b1, nullptr, 1.f, DD, DD, DD, 2*DD, 0, 0, 0);
  gelu_cast<<<dim3(8192), blk, 0, stream>>>(G, g1b, (long)BB*KK*2*DD);
  gemm_nt<128,128,64,64><<<dim3(8,8,1), blk, 0, stream>>>(
      g1b, w2T, out, nullptr, b2, S, 1.f, 2*DD, 2*DD, 2*DD, DD, 0, 0, 0);
}

// Round 3
// 1431.426 us; speedup vs baseline: 1.2021x; 1.2021x over previous
//
#include <hip/hip_runtime.h>
#include <math.h>

typedef _Float16 h16;
typedef __attribute__((ext_vector_type(8))) _Float16 half8;  // 8 fp16 = 4 VGPRs (MFMA A/B frag)
typedef __attribute__((ext_vector_type(4))) float float4v;   // MFMA C/D frag

// Problem constants
#define BB 16
#define NN 4096
#define KK 64
#define DD 1024
#define HH 8

// ---------------------------------------------------------------------------
// Generic NT GEMM:  C[M,N] = scale * (A[M,Kd] · B[N,Kd]^T) + bias[n] (+gelu) + resid
// A, B fp16 row-major (contraction along contiguous inner dim for BOTH).
// Writes Cf (fp32) and/or Ch (fp16). Batch via blockIdx.z strides.
// SWAP: bm on blockIdx.x (use when A-tiles are the unique big operand, so
// consecutive blocks -> distinct A-tiles -> each tile cached on one XCD L2).
// LDS XOR swizzle: k-group g of row r stored at position g^(r&3) — kills the
// half-wave ds_read_b128 bank imbalance (even rows banks 0-3, odd 16-19).
// ---------------------------------------------------------------------------
template<int BM, int BN, int WM, int WN, bool SWAP>
__global__ __launch_bounds__(256)
void gemm_nt(const h16* __restrict__ A, const h16* __restrict__ B,
             float* Cf, h16* Ch,
             const float* __restrict__ bias, const float* resid,
             float scale, int Kd, int lda, int ldb, int ldc,
             long sA, long sB, long sC, int act)
{
  constexpr int BK = 32;
  constexpr int WAVES_N = BN / WN;
  constexpr int TM = WM / 16, TN = WN / 16;
  __shared__ alignas(16) h16 Ast[BM * BK];
  __shared__ alignas(16) h16 Bst[BN * BK];
  const int tid  = threadIdx.x;
  const int lane = tid & 63, wave = tid >> 6;
  const int wm = wave / WAVES_N, wn = wave % WAVES_N;
  const int bn = SWAP ? blockIdx.y : blockIdx.x;
  const int bm = SWAP ? blockIdx.x : blockIdx.y;
  const int bz = blockIdx.z;
  const h16* Ab = A + (long)bz * sA;
  const h16* Bb = B + (long)bz * sB;
  const int rowA0 = bm * BM, rowB0 = bn * BN;
  // staging: chunk = 16 rows (1024 B LDS); lane writes 16 B at +lane*16.
  // lane's LDS slot (row=lane>>2, pos=lane&3) must hold k-group pos^(row&3).
  const int lrow = lane >> 2;
  const int lcol = ((lane & 3) ^ (lrow & 3)) * 8;   // swizzled k-group to fetch

  float4v acc[TM][TN];
  const float4v fzero = {0.f, 0.f, 0.f, 0.f};
  for (int i = 0; i < TM; i++)
    for (int j = 0; j < TN; j++) acc[i][j] = fzero;

  for (int k0 = 0; k0 < Kd; k0 += BK) {
    __syncthreads();
    for (int c = wave; c < BM/16; c += 4) {
      const h16* g = Ab + (long)(rowA0 + c*16 + lrow) * lda + (k0 + lcol);
      __builtin_amdgcn_global_load_lds((__attribute__((address_space(1))) const void*)g,
          (__attribute__((address_space(3))) void*)(Ast + c*512), 16, 0, 0);
    }
    for (int c = wave; c < BN/16; c += 4) {
      const h16* g = Bb + (long)(rowB0 + c*16 + lrow) * ldb + (k0 + lcol);
      __builtin_amdgcn_global_load_lds((__attribute__((address_space(1))) const void*)g,
          (__attribute__((address_space(3))) void*)(Bst + c*512), 16, 0, 0);
    }
    __syncthreads();

    // frag: row fr, k-quad (lane>>4) stored at swizzled pos (lane>>4)^(fr&3)
    const int fr = lane & 15;
    const int sw = (((lane >> 4) ^ (fr & 3)) * 8);
    half8 af[TM], bfr[TN];
    #pragma unroll
    for (int t = 0; t < TM; t++)
      af[t] = *(const half8*)(Ast + (wm*WM + t*16 + fr)*BK + sw);
    #pragma unroll
    for (int u = 0; u < TN; u++)
      bfr[u] = *(const half8*)(Bst + (wn*WN + u*16 + fr)*BK + sw);
    #pragma unroll
    for (int t = 0; t < TM; t++)
      #pragma unroll
      for (int u = 0; u < TN; u++)
        acc[t][u] = __builtin_amdgcn_mfma_f32_16x16x32_f16(af[t], bfr[u], acc[t][u], 0, 0, 0);
  }

  // C/D layout (m89-verified): col = lane&15, row = (lane>>4)*4 + reg
  const int r0 = rowA0 + wm*WM + (lane >> 4) * 4;
  const int c0 = rowB0 + wn*WN + (lane & 15);
  float* Cfb = Cf ? Cf + (long)bz * sC : (float*)0;
  h16*   Chb = Ch ? Ch + (long)bz * sC : (h16*)0;
  const float* rb = resid ? resid + (long)bz * sC : (const float*)0;
  #pragma unroll
  for (int t = 0; t < TM; t++) {
    #pragma unroll
    for (int u = 0; u < TN; u++) {
      const int col = c0 + u*16;
      const float bv = bias ? bias[col] : 0.f;
      #pragma unroll
      for (int r = 0; r < 4; r++) {
        const long idx = (long)(r0 + t*16 + r) * ldc + col;
        float vv = acc[t][u][r] * scale + bv;
        if (act == 1) vv = 0.5f * vv * (1.f + erff(vv * 0.70710678118654752f));
        if (rb) vv += rb[idx];
        if (Cfb) Cfb[idx] = vv;
        if (Chb) Chb[idx] = (h16)vv;
      }
    }
  }
}

// ---------------------------------------------------------------------------
// Fused attn = q·k^T * scale, then softmax over the SLOT axis (rows), write
// aw fp16. BM=64 covers ALL slots -> column softmax is block-local; the 64
// row-values of one column live in 4 lanes (lane^16/^32) x 16 regs.
// grid: (NN/128, 1, BB). A=q[z] 64x1024, B=k[z] rows bn*128..+128.
// ---------------------------------------------------------------------------
__global__ __launch_bounds__(256)
void attn_softmax(const h16* __restrict__ q, const h16* __restrict__ k,
                  h16* __restrict__ aw)
{
  constexpr int BK = 32;
  __shared__ alignas(16) h16 Ast[64 * BK];
  __shared__ alignas(16) h16 Bst[128 * BK];
  const int tid = threadIdx.x;
  const int lane = tid & 63, wave = tid >> 6;
  const int bn = blockIdx.x, bz = blockIdx.z;
  const h16* Ab = q + (long)bz * (KK * DD);
  const h16* Bb = k + (long)bz * ((long)NN * DD);
  const int rowB0 = bn * 128;
  const int lrow = lane >> 2;
  const int lcol = ((lane & 3) ^ (lrow & 3)) * 8;

  float4v acc[4][2];
  const float4v fzero = {0.f, 0.f, 0.f, 0.f};
  for (int i = 0; i < 4; i++)
    for (int j = 0; j < 2; j++) acc[i][j] = fzero;

  for (int k0 = 0; k0 < DD; k0 += BK) {
    __syncthreads();
    if (wave < 4) {   // A: 4 chunks
      const h16* g = Ab + (long)(wave*16 + lrow) * DD + (k0 + lcol);
      __builtin_amdgcn_global_load_lds((__attribute__((address_space(1))) const void*)g,
          (__attribute__((address_space(3))) void*)(Ast + wave*512), 16, 0, 0);
    }
    for (int c = wave; c < 8; c += 4) {   // B: 8 chunks
      const h16* g = Bb + (long)(rowB0 + c*16 + lrow) * DD + (k0 + lcol);
      __builtin_amdgcn_global_load_lds((__attribute__((address_space(1))) const void*)g,
          (__attribute__((address_space(3))) void*)(Bst + c*512), 16, 0, 0);
    }
    __syncthreads();
    const int fr = lane & 15;
    const int sw = (((lane >> 4) ^ (fr & 3)) * 8);
    half8 af[4], bfr[2];
    #pragma unroll
    for (int t = 0; t < 4; t++)
      af[t] = *(const half8*)(Ast + (t*16 + fr)*BK + sw);
    #pragma unroll
    for (int u = 0; u < 2; u++)
      bfr[u] = *(const half8*)(Bst + (wave*32 + u*16 + fr)*BK + sw);
    #pragma unroll
    for (int t = 0; t < 4; t++)
      #pragma unroll
      for (int u = 0; u < 2; u++)
        acc[t][u] = __builtin_amdgcn_mfma_f32_16x16x32_f16(af[t], bfr[u], acc[t][u], 0, 0, 0);
  }

  // softmax over rows (slots) per column; scale = D^-0.5 = 0.03125
  h16* awz = aw + (long)bz * ((long)KK * NN);
  #pragma unroll
  for (int u = 0; u < 2; u++) {
    float e[4][4];
    float mx = -1e30f;
    #pragma unroll
    for (int t = 0; t < 4; t++)
      #pragma unroll
      for (int r = 0; r < 4; r++) {
        e[t][r] = acc[t][u][r] * 0.03125f;
        mx = fmaxf(mx, e[t][r]);
      }
    mx = fmaxf(mx, __shfl_xor(mx, 16));
    mx = fmaxf(mx, __shfl_xor(mx, 32));
    float sum = 0.f;
    #pragma unroll
    for (int t = 0; t < 4; t++)
      #pragma unroll
      for (int r = 0; r < 4; r++) { e[t][r] = __expf(e[t][r] - mx); sum += e[t][r]; }
    sum += __shfl_xor(sum, 16);
    sum += __shfl_xor(sum, 32);
    const float rinv = 1.f / sum;
    const int col = rowB0 + wave*32 + u*16 + (lane & 15);
    #pragma unroll
    for (int t = 0; t < 4; t++)
      #pragma unroll
      for (int r = 0; r < 4; r++) {
        const int row = t*16 + (lane >> 4)*4 + r;
        awz[(long)row * NN + col] = (h16)(e[t][r] * rinv);
      }
  }
}

// ---------------------------------------------------------------------------
// LayerNorm over D=1024 (one block per row). Optional fused add (x + add).
// ---------------------------------------------------------------------------
__global__ __launch_bounds__(256)
void ln_kernel(const float* x, const float* add,
               const float* __restrict__ g, const float* __restrict__ b,
               float* outf, h16* outh)
{
  const int row = blockIdx.x, t = threadIdx.x;
  const long rb_ = (long)row * DD;
  float v[4]; float s = 0.f, s2 = 0.f;
  #pragma unroll
  for (int i = 0; i < 4; i++) {
    const int c = t + i*256;
    float xv = x[rb_ + c];
    if (add) xv += add[rb_ + c];
    v[i] = xv; s += xv; s2 += xv*xv;
  }
  #pragma unroll
  for (int off = 32; off > 0; off >>= 1) {
    s  += __shfl_down(s,  off, 64);
    s2 += __shfl_down(s2, off, 64);
  }
  __shared__ float red[8];
  const int lane = t & 63, w = t >> 6;
  if (lane == 0) { red[w] = s; red[4+w] = s2; }
  __syncthreads();
  const float S  = red[0]+red[1]+red[2]+red[3];
  const float S2 = red[4]+red[5]+red[6]+red[7];
  const float mean = S * (1.f/DD);
  const float var  = S2 * (1.f/DD) - mean*mean;
  const float rinv = rsqrtf(var + 1e-5f);
  #pragma unroll
  for (int i = 0; i < 4; i++) {
    const int c = t + i*256;
    const float y = (v[i] - mean) * rinv * g[c] + b[c];
    if (outf) outf[rb_ + c] = y;
    if (outh) outh[rb_ + c] = (h16)y;
  }
}

// Slot self-attention MHA: one block per (b,h). seq=64, dh=128. fp16 I/O.
__global__ __launch_bounds__(256)
void mha_kernel(const h16* __restrict__ qkv, h16* __restrict__ sa)
{
  const int b = blockIdx.x >> 3, h = blockIdx.x & 7;
  __shared__ h16   mk[64][128];
  __shared__ h16   mv[64][128];
  __shared__ float sc[64][64];
  const int t = threadIdx.x;
  const long base = ((long)b * 64) * (3*DD) + h * 128;
  for (int i = t; i < 64*128; i += 256) {
    const int r = i >> 7, d = i & 127;
    mk[r][d] = qkv[base + (long)r*(3*DD) + DD   + d];
    mv[r][d] = qkv[base + (long)r*(3*DD) + 2*DD + d];
  }
  __syncthreads();
  {  // scores
    const int q = t >> 2, kb2 = (t & 3) * 16;
    float accv[16];
    #pragma unroll
    for (int i = 0; i < 16; i++) accv[i] = 0.f;
    const h16* mq = qkv + base + (long)q * (3*DD);
    for (int d0 = 0; d0 < 128; d0 += 8) {
      float qr[8];
      #pragma unroll
      for (int j = 0; j < 8; j++) qr[j] = (float)mq[d0 + j];
      #pragma unroll
      for (int i = 0; i < 16; i++) {
        float sacc = 0.f;
        #pragma unroll
        for (int j = 0; j < 8; j++) sacc += qr[j] * (float)(mk[kb2+i][d0+j]);
        accv[i] += sacc;
      }
    }
    #pragma unroll
    for (int i = 0; i < 16; i++) sc[q][kb2+i] = accv[i] * 0.088388347648318447f; // 1/sqrt(128)
  }
  __syncthreads();
  if (t < 64) {  // softmax over keys, row t
    float mx = -1e30f;
    for (int i = 0; i < 64; i++) mx = fmaxf(mx, sc[t][i]);
    float sum = 0.f;
    for (int i = 0; i < 64; i++) { const float e = __expf(sc[t][i] - mx); sc[t][i] = e; sum += e; }
    const float r = 1.f / sum;
    for (int i = 0; i < 64; i++) sc[t][i] *= r;
  }
  __syncthreads();
  {  // out
    const int q = t >> 2, d0 = (t & 3) * 32;
    float o[32];
    #pragma unroll
    for (int i = 0; i < 32; i++) o[i] = 0.f;
    for (int k2 = 0; k2 < 64; k2++) {
      const float p = sc[q][k2];
      #pragma unroll
      for (int i = 0; i < 32; i++) o[i] += p * (float)(mv[k2][d0+i]);
    }
    h16* op = sa + ((long)(b*64 + q)) * DD + h*128 + d0;
    #pragma unroll
    for (int i = 0; i < 32; i++) op[i] = (h16)o[i];
  }
}

// fp32 [R,C] -> fp16 [C,R] (weight transpose+cast)
__global__ void transpose_cast(const float* __restrict__ src, h16* __restrict__ dst,
                               int R, int C)
{
  __shared__ float tile[32][33];
  const int c0 = blockIdx.x * 32, r0 = blockIdx.y * 32;
  const int tx = threadIdx.x & 31, ty = threadIdx.x >> 5;
  for (int i = ty; i < 32; i += 8) tile[i][tx] = src[(long)(r0+i)*C + c0 + tx];
  __syncthreads();
  for (int i = ty; i < 32; i += 8) dst[(long)(c0+i)*R + r0 + tx] = (h16)tile[tx][i];
}

__global__ void cast_f32_h16(const float* __restrict__ x, h16* __restrict__ y, long n)
{
  const long i = (long)blockIdx.x * 256 + threadIdx.x;
  if (i < n) y[i] = (h16)x[i];
}

// slots[b*64+k][d] = slot_init[k][d]
__global__ void init_slots(const float* __restrict__ si, float* __restrict__ S)
{
  const long i = (long)blockIdx.x * 256 + threadIdx.x;   // over 1024*1024
  const int row = (int)(i >> 10), d = (int)(i & 1023);
  S[i] = si[((row & 63) << 10) + d];
}

// ---------------------------------------------------------------------------
extern "C" void kernel_launch(void* const* d_in, const int* in_sizes, int n_in,
                              void* d_out, int out_size, void* d_ws, size_t ws_size,
                              hipStream_t stream)
{
  const float* vt        = (const float*)d_in[0];
  const float* slot_init = (const float*)d_in[1];
  const float* ln_vis_g  = (const float*)d_in[2];
  const float* ln_vis_b  = (const float*)d_in[3];
  const float* ln_sl_g   = (const float*)d_in[4];
  const float* ln_sl_b   = (const float*)d_in[5];
  const float* Wq        = (const float*)d_in[6];
  const float* Wk        = (const float*)d_in[7];
  const float* Wv        = (const float*)d_in[8];
  const float* Wo        = (const float*)d_in[9];
  const float* mha_in_w  = (const float*)d_in[10];
  const float* mha_in_b  = (const float*)d_in[11];
  const float* mha_out_w = (const float*)d_in[12];
  const float* mha_out_b = (const float*)d_in[13];
  const float* ln_sa_g   = (const float*)d_in[14];
  const float* ln_sa_b   = (const float*)d_in[15];
  const float* ln_ffn_g  = (const float*)d_in[16];
  const float* ln_ffn_b  = (const float*)d_in[17];
  const float* W1        = (const float*)d_in[18];
  const float* b1        = (const float*)d_in[19];
  const float* W2        = (const float*)d_in[20];
  const float* b2        = (const float*)d_in[21];
  float* out = (float*)d_out;

  // ---- workspace (bump allocator, 256B aligned; total ≈ 464 MB) ----
  char* ws = (char*)d_ws;
  size_t off = 0;
  auto alloc = [&](size_t bytes) -> char* {
    char* p = ws + off; off += (bytes + 255) & ~(size_t)255; return p;
  };
  h16* wqT  = (h16*)alloc((size_t)DD*DD*2);        // [out,in]
  h16* wkT  = (h16*)alloc((size_t)DD*DD*2);
  h16* wvT  = (h16*)alloc((size_t)DD*DD*2);
  h16* woT  = (h16*)alloc((size_t)DD*DD*2);
  h16* w_in = (h16*)alloc((size_t)3*DD*DD*2);      // already [out,in]
  h16* w_ou = (h16*)alloc((size_t)DD*DD*2);
  h16* w1T  = (h16*)alloc((size_t)2*DD*DD*2);      // [2D, D]
  h16* w2T  = (h16*)alloc((size_t)2*DD*DD*2);      // [D, 2D]
  float* S      = (float*)alloc((size_t)BB*KK*DD*4);
  h16*   snb    = (h16*)alloc((size_t)BB*KK*DD*2);
  h16*   qb     = (h16*)alloc((size_t)BB*KK*DD*2);
  h16*   updb   = (h16*)alloc((size_t)BB*KK*DD*2);
  h16*   slotsb = (h16*)alloc((size_t)BB*KK*DD*2);
  h16*   sab    = (h16*)alloc((size_t)BB*KK*DD*2);
  h16*   hb     = (h16*)alloc((size_t)BB*KK*DD*2);
  h16*   g1b    = (h16*)alloc((size_t)BB*KK*2*DD*2);
  h16*   qkvh   = (h16*)alloc((size_t)BB*KK*3*DD*2);
  float* sa2    = (float*)alloc((size_t)BB*KK*DD*4);
  h16*   awb    = (h16*)alloc((size_t)BB*KK*NN*2);  // 8.4 MB
  h16*   vnb    = (h16*)alloc((size_t)BB*NN*DD*2);  // 134 MB
  h16*   kbuf   = (h16*)alloc((size_t)BB*NN*DD*2);  // 134 MB
  h16*   vT     = (h16*)alloc((size_t)BB*NN*DD*2);  // 134 MB, [B][D][N]
  (void)in_sizes; (void)n_in; (void)out_size; (void)ws_size;

  const dim3 blk(256);
  const float* nf = nullptr;

  // ---- weight prep ----
  transpose_cast<<<dim3(32,32,1), blk, 0, stream>>>(Wq, wqT, DD, DD);
  transpose_cast<<<dim3(32,32,1), blk, 0, stream>>>(Wk, wkT, DD, DD);
  transpose_cast<<<dim3(32,32,1), blk, 0, stream>>>(Wv, wvT, DD, DD);
  transpose_cast<<<dim3(32,32,1), blk, 0, stream>>>(Wo, woT, DD, DD);
  transpose_cast<<<dim3(64,32,1), blk, 0, stream>>>(W1, w1T, DD, 2*DD);
  transpose_cast<<<dim3(32,64,1), blk, 0, stream>>>(W2, w2T, 2*DD, DD);
  cast_f32_h16<<<dim3(12288), blk, 0, stream>>>(mha_in_w, w_in, (long)3*DD*DD);
  cast_f32_h16<<<dim3(4096),  blk, 0, stream>>>(mha_out_w, w_ou, (long)DD*DD);
  init_slots<<<dim3(4096), blk, 0, stream>>>(slot_init, S);

  // ---- phase A: vn = LN(vt); k = vn@Wk  [B*N,D]; vT = (vn@Wv)^T  [B][D,N] ----
  ln_kernel<<<dim3(BB*NN), blk, 0, stream>>>(vt, nullptr, ln_vis_g, ln_vis_b, nullptr, vnb);
  // k: A=vnb is the unique big operand -> bm on x (SWAP)
  gemm_nt<128,128,64,64,true><<<dim3(512,8,1), blk, 0, stream>>>(
      vnb, wkT, nullptr, kbuf, nf, nf, 1.f, DD, DD, DD, DD, 0, 0, 0, 0);
  // vT: B=vnb is the unique big operand -> bn on x
  gemm_nt<128,128,64,64,false><<<dim3(32,8,BB), blk, 0, stream>>>(
      wvT, vnb, nullptr, vT, nf, nf, 1.f, DD, DD, DD, NN,
      0, (long)NN*DD, (long)DD*NN, 0);

  // ---- 2 slot-attention iterations ----
  for (int it = 0; it < 2; ++it) {
    ln_kernel<<<dim3(BB*KK), blk, 0, stream>>>(S, nullptr, ln_sl_g, ln_sl_b, nullptr, snb);
    gemm_nt<32,64,16,32,false><<<dim3(16,32,1), blk, 0, stream>>>(     // q = sn @ Wq
        snb, wqT, nullptr, qb, nf, nf, 1.f, DD, DD, DD, DD, 0, 0, 0, 0);
    attn_softmax<<<dim3(32,1,BB), blk, 0, stream>>>(qb, kbuf, awb);    // fused qk^T+softmax
    gemm_nt<32,64,16,32,false><<<dim3(16,2,BB), blk, 0, stream>>>(     // upd = aw · v
        awb, vT, nullptr, updb, nf, nf, 1.f, NN, NN, NN, DD,
        (long)KK*NN, (long)DD*NN, (long)KK*DD, 0);
    gemm_nt<32,64,16,32,false><<<dim3(16,32,1), blk, 0, stream>>>(     // S += upd@Wo (+fp16 copy)
        updb, woT, S, slotsb, nf, S, 1.f, DD, DD, DD, DD, 0, 0, 0, 0);
    gemm_nt<64,128,64,32,false><<<dim3(24,16,1), blk, 0, stream>>>(    // qkv = slots@Win^T + b
        slotsb, w_in, nullptr, qkvh, mha_in_b, nf, 1.f, DD, DD, DD, 3*DD, 0, 0, 0, 0);
    mha_kernel<<<dim3(BB*HH), blk, 0, stream>>>(qkvh, sab);
    gemm_nt<32,64,16,32,false><<<dim3(16,32,1), blk, 0, stream>>>(     // sa2 = sa@Wout^T + b
        sab, w_ou, sa2, nullptr, mha_out_b, nf, 1.f, DD, DD, DD, DD, 0, 0, 0, 0);
    ln_kernel<<<dim3(BB*KK), blk, 0, stream>>>(S, sa2, ln_sa_g, ln_sa_b, S, nullptr);
  }

  // ---- FFN tail: out = S + gelu(LN(S)@W1 + b1)@W2 + b2 ----
  ln_kernel<<<dim3(BB*KK), blk, 0, stream>>>(S, nullptr, ln_ffn_g, ln_ffn_b, nullptr, hb);
  gemm_nt<32,128,32,32,false><<<dim3(16,32,1), blk, 0, stream>>>(      // g1 = gelu(h@W1+b1)
      hb, w1T, nullptr, g1b, b1, nf, 1.f, DD, DD, DD, 2*DD, 0, 0, 0, 1);
  gemm_nt<32,64,16,32,false><<<dim3(16,32,1), blk, 0, stream>>>(       // out = S + g1@W2 + b2
      g1b, w2T, out, nullptr, b2, S, 1.f, 2*DD, 2*DD, 2*DD, DD, 0, 0, 0, 0);
}